// Round 6
// baseline (184.120 us; speedup 1.0000x reference)
//
#include <hip/hip_runtime.h>

// out[n,o] = sum_i x[n,i] * w[o,i] * att[n,i,o] + bias[o]
// N=256, I=1024, O=1024, fp32. HBM-bound on the 1.074 GB attention tensor.
//
// R6: R5 structure with NB=2 (grid 8x128 = 1024 blocks = 16 waves/CU) to
// test the TLP/latency-hiding hypothesis for the last ~6%. Same coalesced
// wT + nontemporal att streaming + fused intra-block LDS reduction.

typedef float f32x4 __attribute__((ext_vector_type(4)));

constexpr int Nn = 256;
constexpr int Ii = 1024;
constexpr int Oo = 1024;
constexpr int NB = 2;        // samples per block
constexpr int OCHUNK = 128;  // o per block
constexpr int NSUB = 8;      // i-subgroups per block (32 lanes each)
constexpr int ISUB = Ii / NSUB;   // 128
constexpr int TPB = 256;

// ---- w[o][i] -> wT[i][o], 32x32 LDS tiles ----
__global__ __launch_bounds__(256)
void transpose_w_kernel(const float* __restrict__ w, float* __restrict__ wT) {
    __shared__ float tile[32][33];
    const int bi = blockIdx.x * 32;
    const int bo = blockIdx.y * 32;
    const int tx = threadIdx.x % 32;
    const int ty = threadIdx.x / 32;
    #pragma unroll
    for (int r = 0; r < 4; ++r)
        tile[ty + 8 * r][tx] = w[(size_t)(bo + ty + 8 * r) * Ii + bi + tx];
    __syncthreads();
    #pragma unroll
    for (int r = 0; r < 4; ++r)
        wT[(size_t)(bi + ty + 8 * r) * Oo + bo + tx] = tile[tx][ty + 8 * r];
}

__global__ __launch_bounds__(TPB)
void attn_fused_kernel(const float* __restrict__ x,
                       const float* __restrict__ att,
                       const float* __restrict__ wT,
                       const float* __restrict__ bias,
                       float* __restrict__ out) {
    __shared__ float xs[NB][Ii];               // 8 KB
    __shared__ float red[NSUB][NB * OCHUNK];   // 8 KB

    const int ocx = blockIdx.x;                // o-chunk
    const int ng  = blockIdx.y;
    const int tid = threadIdx.x;
    const int g   = tid >> 5;                  // subgroup = i-slice owner
    const int t   = tid & 31;
    const int n0  = ng * NB;
    const int oc0 = ocx * OCHUNK;

    // stage x[n0..n0+1][:] -> LDS: 512 f32x4, 2 per thread
    {
        const f32x4* xsrc = reinterpret_cast<const f32x4*>(x + (size_t)n0 * Ii);
        f32x4* xdst = reinterpret_cast<f32x4*>(&xs[0][0]);
        xdst[tid]       = xsrc[tid];
        xdst[tid + 256] = xsrc[tid + 256];
    }
    __syncthreads();

    const int i0 = g * ISUB;
    const int o0 = oc0 + t * 4;

    const float* a0p = att + ((size_t)(n0 + 0) * Ii + i0) * Oo + o0;
    const float* a1p = att + ((size_t)(n0 + 1) * Ii + i0) * Oo + o0;
    const float* wtp = wT + (size_t)i0 * Oo + o0;

    f32x4 acc0 = {0.f, 0.f, 0.f, 0.f};
    f32x4 acc1 = {0.f, 0.f, 0.f, 0.f};

    for (int ii = 0; ii < ISUB; ii += 4) {
        f32x4 xv0 = *reinterpret_cast<const f32x4*>(&xs[0][i0 + ii]);
        f32x4 xv1 = *reinterpret_cast<const f32x4*>(&xs[1][i0 + ii]);
        #pragma unroll
        for (int e = 0; e < 4; ++e) {
            const size_t roff = (size_t)(ii + e) * Oo;
            f32x4 wv = *reinterpret_cast<const f32x4*>(wtp + roff);
            f32x4 b0 = __builtin_nontemporal_load(
                reinterpret_cast<const f32x4*>(a0p + roff));
            f32x4 b1 = __builtin_nontemporal_load(
                reinterpret_cast<const f32x4*>(a1p + roff));
            #pragma unroll
            for (int k = 0; k < 4; ++k) {
                acc0[k] = fmaf(xv0[e] * wv[k], b0[k], acc0[k]);
                acc1[k] = fmaf(xv1[e] * wv[k], b1[k], acc1[k]);
            }
        }
    }

    // per-subgroup partials -> LDS
    *reinterpret_cast<f32x4*>(&red[g][0 * OCHUNK + t * 4]) = acc0;
    *reinterpret_cast<f32x4*>(&red[g][1 * OCHUNK + t * 4]) = acc1;
    __syncthreads();

    // cross-subgroup reduce: NB*OCHUNK = 256 outputs, 1 per thread
    {
        const int nb = tid >> 7;
        const int ol = tid & 127;
        float s = 0.f;
        #pragma unroll
        for (int g2 = 0; g2 < NSUB; ++g2)
            s += red[g2][tid];
        s += bias[oc0 + ol];
        out[(size_t)(n0 + nb) * Oo + oc0 + ol] = s;
    }
}

extern "C" void kernel_launch(void* const* d_in, const int* in_sizes, int n_in,
                              void* d_out, int out_size, void* d_ws, size_t ws_size,
                              hipStream_t stream) {
    const float* x    = (const float*)d_in[0];
    const float* att  = (const float*)d_in[1];
    const float* w    = (const float*)d_in[2];
    const float* bias = (const float*)d_in[3];
    float* out        = (float*)d_out;
    float* wT         = (float*)d_ws;    // 4 MB

    dim3 tgrid(Ii / 32, Oo / 32);
    transpose_w_kernel<<<tgrid, 256, 0, stream>>>(w, wT);

    dim3 grid(Oo / OCHUNK, Nn / NB);     // (8, 128) = 1024 blocks
    attn_fused_kernel<<<grid, TPB, 0, stream>>>(x, att, wT, bias, out);
}

// Round 7
// 182.407 us; speedup vs baseline: 1.0094x; 1.0094x over previous
//
#include <hip/hip_runtime.h>

// out[n,o] = sum_i x[n,i] * w[o,i] * att[n,i,o] + bias[o]
// N=256, I=1024, O=1024, fp32. HBM-bound on the 1.074 GB attention tensor.
//
// FINAL (revert to R5, best measured 182.6 us ~= read-stream roofline):
// - w pre-transposed to wT[i][o] so ALL global streams are 16B/lane coalesced
//   (R2->R3: scattered weight reads were the 350->202 us bottleneck).
// - NB=4 samples/block amortizes wT reads 4x (R4: 202->191).
// - Single fused kernel: 8 subgroups x 32 lanes own 128-wide i-slices,
//   intra-block LDS reduction + bias epilogue — no partial round-trip (R5:
//   191->183).
// - att loads nontemporal so the 1 GB stream doesn't evict L2-resident wT.
// - NB=2 TLP probe (R6) was neutral-negative: latency-hiding is NOT the
//   limiter; effective 6.1 TB/s =~ 97% of the 6.29 TB/s measured read ceiling.

typedef float f32x4 __attribute__((ext_vector_type(4)));

constexpr int Nn = 256;
constexpr int Ii = 1024;
constexpr int Oo = 1024;
constexpr int NB = 4;        // samples per block
constexpr int OCHUNK = 128;  // o per block
constexpr int NSUB = 8;      // i-subgroups per block (32 lanes each)
constexpr int ISUB = Ii / NSUB;   // 128
constexpr int TPB = 256;

// ---- w[o][i] -> wT[i][o], 32x32 LDS tiles ----
__global__ __launch_bounds__(256)
void transpose_w_kernel(const float* __restrict__ w, float* __restrict__ wT) {
    __shared__ float tile[32][33];
    const int bi = blockIdx.x * 32;
    const int bo = blockIdx.y * 32;
    const int tx = threadIdx.x % 32;
    const int ty = threadIdx.x / 32;
    #pragma unroll
    for (int r = 0; r < 4; ++r)
        tile[ty + 8 * r][tx] = w[(size_t)(bo + ty + 8 * r) * Ii + bi + tx];
    __syncthreads();
    #pragma unroll
    for (int r = 0; r < 4; ++r)
        wT[(size_t)(bi + ty + 8 * r) * Oo + bo + tx] = tile[tx][ty + 8 * r];
}

__global__ __launch_bounds__(TPB)
void attn_fused_kernel(const float* __restrict__ x,
                       const float* __restrict__ att,
                       const float* __restrict__ wT,
                       const float* __restrict__ bias,
                       float* __restrict__ out) {
    __shared__ float xs[NB][Ii];               // 16 KB
    __shared__ float red[NSUB][NB * OCHUNK];   // 16 KB

    const int ocx = blockIdx.x;                // o-chunk
    const int ng  = blockIdx.y;
    const int tid = threadIdx.x;
    const int g   = tid >> 5;                  // subgroup = i-slice owner
    const int t   = tid & 31;
    const int n0  = ng * NB;
    const int oc0 = ocx * OCHUNK;

    // stage x[n0..n0+3][:] -> LDS (coalesced f32x4 per row)
    #pragma unroll
    for (int nb = 0; nb < NB; ++nb)
        reinterpret_cast<f32x4*>(&xs[nb][0])[tid] =
            reinterpret_cast<const f32x4*>(x + (size_t)(n0 + nb) * Ii)[tid];
    __syncthreads();

    const int i0 = g * ISUB;
    const int o0 = oc0 + t * 4;

    const float* a0p = att + ((size_t)(n0 + 0) * Ii + i0) * Oo + o0;
    const float* a1p = att + ((size_t)(n0 + 1) * Ii + i0) * Oo + o0;
    const float* a2p = att + ((size_t)(n0 + 2) * Ii + i0) * Oo + o0;
    const float* a3p = att + ((size_t)(n0 + 3) * Ii + i0) * Oo + o0;
    const float* wtp = wT + (size_t)i0 * Oo + o0;

    f32x4 acc0 = {0.f, 0.f, 0.f, 0.f};
    f32x4 acc1 = {0.f, 0.f, 0.f, 0.f};
    f32x4 acc2 = {0.f, 0.f, 0.f, 0.f};
    f32x4 acc3 = {0.f, 0.f, 0.f, 0.f};

    for (int ii = 0; ii < ISUB; ii += 4) {
        f32x4 xv0 = *reinterpret_cast<const f32x4*>(&xs[0][i0 + ii]);
        f32x4 xv1 = *reinterpret_cast<const f32x4*>(&xs[1][i0 + ii]);
        f32x4 xv2 = *reinterpret_cast<const f32x4*>(&xs[2][i0 + ii]);
        f32x4 xv3 = *reinterpret_cast<const f32x4*>(&xs[3][i0 + ii]);
        #pragma unroll
        for (int e = 0; e < 4; ++e) {
            const size_t roff = (size_t)(ii + e) * Oo;
            f32x4 wv = *reinterpret_cast<const f32x4*>(wtp + roff);
            f32x4 b0 = __builtin_nontemporal_load(
                reinterpret_cast<const f32x4*>(a0p + roff));
            f32x4 b1 = __builtin_nontemporal_load(
                reinterpret_cast<const f32x4*>(a1p + roff));
            f32x4 b2 = __builtin_nontemporal_load(
                reinterpret_cast<const f32x4*>(a2p + roff));
            f32x4 b3 = __builtin_nontemporal_load(
                reinterpret_cast<const f32x4*>(a3p + roff));
            #pragma unroll
            for (int k = 0; k < 4; ++k) {
                acc0[k] = fmaf(xv0[e] * wv[k], b0[k], acc0[k]);
                acc1[k] = fmaf(xv1[e] * wv[k], b1[k], acc1[k]);
                acc2[k] = fmaf(xv2[e] * wv[k], b2[k], acc2[k]);
                acc3[k] = fmaf(xv3[e] * wv[k], b3[k], acc3[k]);
            }
        }
    }

    // per-subgroup partials -> LDS
    *reinterpret_cast<f32x4*>(&red[g][0 * OCHUNK + t * 4]) = acc0;
    *reinterpret_cast<f32x4*>(&red[g][1 * OCHUNK + t * 4]) = acc1;
    *reinterpret_cast<f32x4*>(&red[g][2 * OCHUNK + t * 4]) = acc2;
    *reinterpret_cast<f32x4*>(&red[g][3 * OCHUNK + t * 4]) = acc3;
    __syncthreads();

    // cross-subgroup reduce: 512 outputs, 2 per thread (float2)
    {
        const int fl = tid * 2;          // nb*128 + ol, pair stays within nb
        const int nb = fl >> 7;
        const int ol = fl & 127;
        float sx = 0.f, sy = 0.f;
        #pragma unroll
        for (int g2 = 0; g2 < NSUB; ++g2) {
            const float* rp = &red[g2][fl];
            sx += rp[0];
            sy += rp[1];
        }
        sx += bias[oc0 + ol];
        sy += bias[oc0 + ol + 1];
        float2 res = {sx, sy};
        *reinterpret_cast<float2*>(out + (size_t)(n0 + nb) * Oo + oc0 + ol) = res;
    }
}

extern "C" void kernel_launch(void* const* d_in, const int* in_sizes, int n_in,
                              void* d_out, int out_size, void* d_ws, size_t ws_size,
                              hipStream_t stream) {
    const float* x    = (const float*)d_in[0];
    const float* att  = (const float*)d_in[1];
    const float* w    = (const float*)d_in[2];
    const float* bias = (const float*)d_in[3];
    float* out        = (float*)d_out;
    float* wT         = (float*)d_ws;    // 4 MB

    dim3 tgrid(Ii / 32, Oo / 32);
    transpose_w_kernel<<<tgrid, 256, 0, stream>>>(w, wT);

    dim3 grid(Oo / OCHUNK, Nn / NB);     // (8, 64) = 512 blocks
    attn_fused_kernel<<<grid, TPB, 0, stream>>>(x, att, wT, bias, out);
}